// Round 14
// baseline (80.597 us; speedup 1.0000x reference)
//
#include <hip/hip_runtime.h>
#include <float.h>

// ChamferLoss via MFMA, verts-as-rows, Q=8 point-tiles/wave.
// B=4, N=16384, M=4096, fp32 in/out.
// loss[b] = (1/N) * sum_n min_m max(||p_bn - v_bm||^2, 0)
//
// d2 = pp + (v2 - 2 p.v). Bracket on the MATRIX pipe via split-bf16 in K=16
// of mfma_f32_32x32x16_bf16 (encoding + layouts validated R6-R13, absmax 0):
//   A row (VERT):   [-2vh x3, -2vh x3, -2vl x3, v2h, v2l, 0...]
//   B col (POINT):  [ph x3, pl x3, ph x3, 1, 1, 0...]
// A lane's 16 C-regs = 16 verts of ONE point (col = lane&31) -> min folds
// across regs via v_min3_f32; lane L / L+32 merge via one shfl_xor(32).
//
// R14 cycle budget per CU (the lever left after 8 structural variants all
// landed 74-79 us): MFMA 8.2K cyc is the fixed floor; R10 spent 12.3K cyc
// on ds_read_b128 (one per MFMA). Q=8 -> one vert ds_read feeds 8 MFMAs:
// ds-read 12.3K -> 1.5K cyc, staging copy 64 MB -> 8 MB. MFMA pipe becomes
// the binding term. bP[8] may sit in AGPRs (free as MFMA operands, gfx950
// unified file). 1024 blocks = 4/CU, 8 KB LDS.

typedef __bf16 bf16x8 __attribute__((ext_vector_type(8)));
typedef float  f32x16 __attribute__((ext_vector_type(16)));

constexpr int B = 4, N = 16384, M = 4096;
constexpr int BN = B * N;
constexpr int NCHUNK = 16;
constexpr int CHUNK_V = M / NCHUNK;      // 256 verts per chunk
constexpr int TILES = CHUNK_V / 32;      // 8 vert tiles per chunk
constexpr int TPB = 256;                 // 4 waves
constexpr int Q = 8;                     // point tiles per wave
constexpr int PPW = 32 * Q;              // 256 points per wave
constexpr int PPB = 4 * PPW;             // 1024 points per block
constexpr int PBLK = BN / PPB;           // 64 point-blocks (16 per batch)
// grid = PBLK * NCHUNK = 1024 blocks
constexpr size_t BFRAG_BYTES = (size_t)B * M * 32;   // 512 KB in ws

// ---- Pre-pass: per-vert A-frag K-vectors; zero out[]. ----
// Vert m of batch b -> byte offset:
//   b*131072 + chunk*8192 + tile*1024 + (m&31)*16 ; K8-15 at +512
__global__ __launch_bounds__(256) void chamfer_pre(
    const float* __restrict__ tv, unsigned char* __restrict__ bfr,
    float* __restrict__ out)
{
    if (blockIdx.x == 0 && threadIdx.x < B) out[threadIdx.x] = 0.0f;
    int i = blockIdx.x * 256 + threadIdx.x;      // 0..B*M-1
    int m = i & (M - 1);
    float x = tv[3 * i + 0], y = tv[3 * i + 1], z = tv[3 * i + 2];
    __bf16 xh = (__bf16)x, yh = (__bf16)y, zh = (__bf16)z;
    float xhf = (float)xh, yhf = (float)yh, zhf = (float)zh;
    __bf16 xl = (__bf16)(x - xhf), yl = (__bf16)(y - yhf), zl = (__bf16)(z - zhf);
    float v2 = fmaf(x, x, fmaf(y, y, z * z));
    __bf16 v2h = (__bf16)v2;
    __bf16 v2l = (__bf16)(v2 - (float)v2h);
    __bf16 zero = (__bf16)0.0f;

    bf16x8 h0, h1;
    h0[0] = (__bf16)(-2.0f * xhf); h0[1] = (__bf16)(-2.0f * yhf);
    h0[2] = (__bf16)(-2.0f * zhf);
    h0[3] = h0[0]; h0[4] = h0[1]; h0[5] = h0[2];
    h0[6] = (__bf16)(-2.0f * (float)xl); h0[7] = (__bf16)(-2.0f * (float)yl);
    h1[0] = (__bf16)(-2.0f * (float)zl); h1[1] = v2h; h1[2] = v2l;
    h1[3] = zero; h1[4] = zero; h1[5] = zero; h1[6] = zero; h1[7] = zero;

    int chunk = m >> 8, local = m & (CHUNK_V - 1), tile = local >> 5;
    size_t base = (size_t)(i >> 12) * 131072 + (size_t)chunk * 8192
                + tile * 1024 + (m & 31) * 16;
    *(bf16x8*)(bfr + base)       = h0;
    *(bf16x8*)(bfr + base + 512) = h1;
}

// ---- Main: 1024 blocks = 64 point-blocks x 16 chunks, 4 blocks/CU. ----
// Wave w: 256 points (8 col-tiles) vs the block's 256-vert chunk (8 tiles).
// partial[chunk][point] = pp + min over chunk verts of (v2 - 2 p.v).
__global__ __launch_bounds__(TPB) void chamfer_mfma(
    const float* __restrict__ src, const unsigned char* __restrict__ bfr,
    float* __restrict__ partial)
{
    __shared__ uint4 lds4[512];                  // 8 KB vert A-frags
    const char* ldsc = (const char*)lds4;
    const int blk   = blockIdx.x;
    const int chunk = blk & 15;
    const int pblk  = blk >> 4;                  // 0..63
    const int b     = pblk >> 4;                 // 16 point-blocks per batch
    const int t     = threadIdx.x;
    const int w     = t >> 6, L = t & 63;
    const int half  = L >> 5, c = L & 31;

    // Stage this chunk's 8 KB of vert A-frags (coalesced identity copy).
    const uint4* gsrc = (const uint4*)(bfr + (size_t)b * 131072 + (size_t)chunk * 8192);
    lds4[t]       = gsrc[t];
    lds4[256 + t] = gsrc[256 + t];

    // B-frags for this wave's Q=8 point tiles (col = c), in registers/AGPRs.
    const int pbase = pblk * PPB + w * PPW;
    __bf16 one = (__bf16)1.0f, zero = (__bf16)0.0f;
    bf16x8 bP[Q];
    float pp[Q];
#pragma unroll
    for (int q = 0; q < Q; ++q) {
        const int gp = pbase + q * 32 + c;
        float x = src[3 * gp], y = src[3 * gp + 1], z = src[3 * gp + 2];
        pp[q] = fmaf(x, x, fmaf(y, y, z * z));
        __bf16 xh = (__bf16)x, yh = (__bf16)y, zh = (__bf16)z;
        __bf16 xl = (__bf16)(x - (float)xh), yl = (__bf16)(y - (float)yh),
               zl = (__bf16)(z - (float)zh);
        bf16x8 f;
        if (half == 0) { f[0]=xh; f[1]=yh; f[2]=zh; f[3]=xl; f[4]=yl; f[5]=zl; f[6]=xh; f[7]=yh; }
        else { f[0]=zh; f[1]=one; f[2]=one; f[3]=zero; f[4]=zero; f[5]=zero; f[6]=zero; f[7]=zero; }
        bP[q] = f;
    }

    float mn[Q][8];
#pragma unroll
    for (int q = 0; q < Q; ++q)
#pragma unroll
        for (int u = 0; u < 8; ++u) mn[q][u] = FLT_MAX;
    f32x16 zeroC;
#pragma unroll
    for (int r = 0; r < 16; ++r) zeroC[r] = 0.0f;

    __syncthreads();

    // K-loop: 8 tiles x (1 ds_read_b128 -> 8 independent MFMAs -> 64 min3).
    const int laneoff = half * 512 + c * 16;
#pragma unroll 2
    for (int tl = 0; tl < TILES; ++tl) {
        bf16x8 av = *(const bf16x8*)(ldsc + tl * 1024 + laneoff);
#pragma unroll
        for (int q = 0; q < Q; ++q) {
            f32x16 C = __builtin_amdgcn_mfma_f32_32x32x16_bf16(av, bP[q], zeroC, 0, 0, 0);
#pragma unroll
            for (int u = 0; u < 8; ++u)
                mn[q][u] = fminf(fminf(mn[q][u], C[2 * u]), C[2 * u + 1]);
        }
    }

    // Epilogue: fold 8 accumulators per tile, merge lane halves (L vs L+32
    // hold the same point col), add pp, store 256 consecutive floats/wave.
    float* pout = partial + (size_t)chunk * BN + pbase;
#pragma unroll
    for (int q = 0; q < Q; ++q) {
        float a = fminf(fminf(mn[q][0], mn[q][1]), fminf(mn[q][2], mn[q][3]));
        float d = fminf(fminf(mn[q][4], mn[q][5]), fminf(mn[q][6], mn[q][7]));
        float x = fminf(a, d);
        float m = fminf(x, __shfl_xor(x, 32, 64)) + pp[q];
        if (L < 32) pout[q * 32 + c] = m;
    }
}

// ---- Reduce: min over 16 chunks, clamp, per-batch mean. ----
__global__ __launch_bounds__(256) void chamfer_reduce(
    const float* __restrict__ partial, float* __restrict__ out)
{
    const int p = blockIdx.x * 256 + threadIdx.x;
    const int b = blockIdx.x >> 6;               // 64 blocks per batch
    float m = FLT_MAX;
#pragma unroll
    for (int cgr = 0; cgr < NCHUNK; ++cgr)
        m = fminf(m, partial[(size_t)cgr * BN + p]);
    float sum = fmaxf(m, 0.0f);

    for (int off = 32; off > 0; off >>= 1)
        sum += __shfl_down(sum, off, 64);
    __shared__ float acc[4];
    if ((threadIdx.x & 63) == 0) acc[threadIdx.x >> 6] = sum;
    __syncthreads();
    if (threadIdx.x == 0) {
        float s = acc[0] + acc[1] + acc[2] + acc[3];
        atomicAdd(&out[b], s * (1.0f / N));
    }
}

extern "C" void kernel_launch(void* const* d_in, const int* in_sizes, int n_in,
                              void* d_out, int out_size, void* d_ws, size_t ws_size,
                              hipStream_t stream) {
    const float* src = (const float*)d_in[0];    // (B, N, 3) fp32
    const float* tv  = (const float*)d_in[1];    // (B, M, 3) fp32
    float* out = (float*)d_out;                  // (B,) fp32
    unsigned char* bfr = (unsigned char*)d_ws;   // 512 KB vert A-frags
    float* partial = (float*)((char*)d_ws + BFRAG_BYTES);  // 4 MB

    chamfer_pre   <<<(B * M) / 256, 256, 0, stream>>>(tv, bfr, out);
    chamfer_mfma  <<<PBLK * NCHUNK, TPB, 0, stream>>>(src, bfr, partial);
    chamfer_reduce<<<BN / 256, 256, 0, stream>>>(partial, out);
}

// Round 15
// 74.184 us; speedup vs baseline: 1.0865x; 1.0865x over previous
//
#include <hip/hip_runtime.h>
#include <float.h>

// ChamferLoss via MFMA, verts-as-rows (R10, session best: 74.2 us).
// B=4, N=16384, M=4096, fp32 in/out.
// loss[b] = (1/N) * sum_n min_m max(||p_bn - v_bm||^2, 0)
//
// d2 = pp + (v2 - 2 p.v). Bracket on the MATRIX pipe via split-bf16 in K=16
// of mfma_f32_32x32x16_bf16 (encoding validated R6-R14, absmax 0.0):
//   A row (VERT):   [-2vh x3, -2vh x3, -2vl x3, v2h, v2l, 0...]
//   B col (POINT):  [ph x3, pl x3, ph x3, 1, 1, 0...]
// A lane's 16 C-regs = 16 verts of ONE point (col = lane&31) -> min folds
// across regs via v_min3_f32; lane L / L+32 merge via one shfl_xor(32).
//
// Session post-mortem (R1-R14): nine structural variants (VALU and MFMA
// formulations, LDS/L2/scalar vert sources, Q=1/2/4/8 tiles per wave,
// 1/2/3 dispatches, 2-32 waves/CU) all land 74-81 us. Controllable kernel
// time (~33 us after the harness's fixed ~41 us ws-poison fill) is a
// latency + short-kernel clock-ramp floor (R12 counters: MfmaUtil 5%,
// VALUBusy 17%, Occ 16% on a directly-measured main), not a throughput
// wall. This file is the best-measured configuration, resubmitted.

typedef __bf16 bf16x8 __attribute__((ext_vector_type(8)));
typedef float  f32x16 __attribute__((ext_vector_type(16)));

constexpr int B = 4, N = 16384, M = 4096;
constexpr int BN = B * N;
constexpr int NCHUNK = 8;
constexpr int CHUNK_V = M / NCHUNK;          // 512 verts per chunk
constexpr int TILES = CHUNK_V / 32;          // 16 vert tiles per chunk
constexpr int TPB = 256;                     // 4 waves x 32 points
constexpr int PPB = 128;                     // points per block
constexpr int PBLK = BN / PPB;               // 512 point-blocks
constexpr size_t BFRAG_BYTES = (size_t)B * M * 32;   // 512 KB in ws

// ---- Pre-pass: per-vert A-frag K-vectors; zero out[]. ----
// Vert m of batch b -> byte offset:
//   b*131072 + chunk*16384 + tile*1024 + khalf*512 + row*16
__global__ __launch_bounds__(256) void chamfer_pre(
    const float* __restrict__ tv, unsigned char* __restrict__ bfr,
    float* __restrict__ out)
{
    if (blockIdx.x == 0 && threadIdx.x < B) out[threadIdx.x] = 0.0f;
    int i = blockIdx.x * 256 + threadIdx.x;      // 0..B*M-1
    int m = i & (M - 1);
    float x = tv[3 * i + 0], y = tv[3 * i + 1], z = tv[3 * i + 2];
    __bf16 xh = (__bf16)x, yh = (__bf16)y, zh = (__bf16)z;
    float xhf = (float)xh, yhf = (float)yh, zhf = (float)zh;
    __bf16 xl = (__bf16)(x - xhf), yl = (__bf16)(y - yhf), zl = (__bf16)(z - zhf);
    float v2 = fmaf(x, x, fmaf(y, y, z * z));
    __bf16 v2h = (__bf16)v2;
    __bf16 v2l = (__bf16)(v2 - (float)v2h);
    __bf16 zero = (__bf16)0.0f;

    bf16x8 h0, h1;
    h0[0] = (__bf16)(-2.0f * xhf); h0[1] = (__bf16)(-2.0f * yhf);
    h0[2] = (__bf16)(-2.0f * zhf);
    h0[3] = h0[0]; h0[4] = h0[1]; h0[5] = h0[2];
    h0[6] = (__bf16)(-2.0f * (float)xl); h0[7] = (__bf16)(-2.0f * (float)yl);
    h1[0] = (__bf16)(-2.0f * (float)zl); h1[1] = v2h; h1[2] = v2l;
    h1[3] = zero; h1[4] = zero; h1[5] = zero; h1[6] = zero; h1[7] = zero;

    int chunk = m >> 9, local = m & (CHUNK_V - 1), tile = local >> 5, r = m & 31;
    size_t base = (size_t)(i >> 12) * 131072 + (size_t)chunk * 16384
                + tile * 1024 + r * 16;
    *(bf16x8*)(bfr + base)       = h0;
    *(bf16x8*)(bfr + base + 512) = h1;
}

// ---- Main: 4096 blocks = 512 point-blocks x 8 chunks. ----
// Wave w: 32 points (cols) vs the block's 512-vert chunk (16 tiles).
// partial[chunk][point] = pp + min over chunk verts of (v2 - 2 p.v).
__global__ __launch_bounds__(TPB) void chamfer_mfma(
    const float* __restrict__ src, const unsigned char* __restrict__ bfr,
    float* __restrict__ partial)
{
    __shared__ uint4 lds4[1024];                 // 16 KB vert A-frags
    const char* ldsc = (const char*)lds4;
    const int blk   = blockIdx.x;
    const int chunk = blk & 7;
    const int pblk  = blk >> 3;                  // 0..511
    const int b     = pblk >> 7;                 // 128 point-blocks per batch
    const int t     = threadIdx.x;
    const int w     = t >> 6, L = t & 63;
    const int half  = L >> 5, c = L & 31;

    // Stage this chunk's 16 KB of vert A-frags (coalesced identity copy).
    const uint4* gsrc = (const uint4*)(bfr + (size_t)b * 131072 + (size_t)chunk * 16384);
#pragma unroll
    for (int i = 0; i < 4; ++i) lds4[i * 256 + t] = gsrc[i * 256 + t];

    // B-frag: this lane's point (col = c), split-bf16 encoding.
    const int gp = pblk * PPB + w * 32 + c;
    float ax = src[3 * gp], ay = src[3 * gp + 1], az = src[3 * gp + 2];
    float pp = fmaf(ax, ax, fmaf(ay, ay, az * az));
    __bf16 one = (__bf16)1.0f, zero = (__bf16)0.0f;
    bf16x8 bP;
    {
        __bf16 xh = (__bf16)ax, yh = (__bf16)ay, zh = (__bf16)az;
        __bf16 xl = (__bf16)(ax - (float)xh), yl = (__bf16)(ay - (float)yh),
               zl = (__bf16)(az - (float)zh);
        if (half == 0) { bP[0]=xh; bP[1]=yh; bP[2]=zh; bP[3]=xl; bP[4]=yl; bP[5]=zl; bP[6]=xh; bP[7]=yh; }
        else { bP[0]=zh; bP[1]=one; bP[2]=one; bP[3]=zero; bP[4]=zero; bP[5]=zero; bP[6]=zero; bP[7]=zero; }
    }

    float mn[8];
    f32x16 zeroC;
#pragma unroll
    for (int u = 0; u < 8; ++u) mn[u] = FLT_MAX;
#pragma unroll
    for (int r = 0; r < 16; ++r) zeroC[r] = 0.0f;

    __syncthreads();

    // Inner loop: 1 ds_read_b128 (vert frag) + 1 MFMA + 8 v_min3_f32.
    const int laneoff = half * 512 + c * 16;
#pragma unroll 4
    for (int tl = 0; tl < TILES; ++tl) {
        bf16x8 av = *(const bf16x8*)(ldsc + tl * 1024 + laneoff);
        f32x16 C = __builtin_amdgcn_mfma_f32_32x32x16_bf16(av, bP, zeroC, 0, 0, 0);
#pragma unroll
        for (int u = 0; u < 8; ++u)
            mn[u] = fminf(fminf(mn[u], C[2 * u]), C[2 * u + 1]);   // v_min3
    }

    // Epilogue: fold 8 accumulators in-lane, merge halves (L vs L+32 hold
    // the same point), add pp, coalesced store by half-0 lanes.
    float m01 = fminf(fminf(mn[0], mn[1]), fminf(mn[2], mn[3]));
    float m23 = fminf(fminf(mn[4], mn[5]), fminf(mn[6], mn[7]));
    float m = fminf(m01, m23);
    m = fminf(m, __shfl_xor(m, 32, 64));
    if (L < 32)
        partial[(size_t)chunk * BN + gp] = m + pp;
}

// ---- Reduce: min over 8 chunks, clamp, per-batch mean. ----
__global__ __launch_bounds__(256) void chamfer_reduce(
    const float* __restrict__ partial, float* __restrict__ out)
{
    const int p = blockIdx.x * 256 + threadIdx.x;
    const int b = blockIdx.x >> 6;               // 64 blocks per batch
    float m = FLT_MAX;
#pragma unroll
    for (int cgr = 0; cgr < NCHUNK; ++cgr)
        m = fminf(m, partial[(size_t)cgr * BN + p]);
    float sum = fmaxf(m, 0.0f);

    for (int off = 32; off > 0; off >>= 1)
        sum += __shfl_down(sum, off, 64);
    __shared__ float acc[4];
    if ((threadIdx.x & 63) == 0) acc[threadIdx.x >> 6] = sum;
    __syncthreads();
    if (threadIdx.x == 0) {
        float s = acc[0] + acc[1] + acc[2] + acc[3];
        atomicAdd(&out[b], s * (1.0f / N));
    }
}

extern "C" void kernel_launch(void* const* d_in, const int* in_sizes, int n_in,
                              void* d_out, int out_size, void* d_ws, size_t ws_size,
                              hipStream_t stream) {
    const float* src = (const float*)d_in[0];    // (B, N, 3) fp32
    const float* tv  = (const float*)d_in[1];    // (B, M, 3) fp32
    float* out = (float*)d_out;                  // (B,) fp32
    unsigned char* bfr = (unsigned char*)d_ws;   // 512 KB vert A-frags
    float* partial = (float*)((char*)d_ws + BFRAG_BYTES);  // 2 MB

    chamfer_pre   <<<(B * M) / 256, 256, 0, stream>>>(tv, bfr, out);
    chamfer_mfma  <<<PBLK * NCHUNK, TPB, 0, stream>>>(src, bfr, partial);
    chamfer_reduce<<<BN / 256, 256, 0, stream>>>(partial, out);
}